// Round 6
// baseline (1246.774 us; speedup 1.0000x reference)
//
#include <hip/hip_runtime.h>
#include <math.h>

#define NTOK 13824            // 24*24*24
#define MTOT 27648            // B*NTOK
#define BATCH 2
#define CIN 128
#define DMODEL 256
#define NHEAD 8
#define NLAYERS 4
#define DFF 512

typedef float f32x4 __attribute__((ext_vector_type(4)));
typedef __bf16 bf16x8 __attribute__((ext_vector_type(8)));
typedef __attribute__((address_space(1))) void gvoid;
typedef __attribute__((address_space(3))) void lvoid;

// async global->LDS, 16B per lane. LDS dest must be uniform-base + lane*16.
#define GLDS16(g, l) __builtin_amdgcn_global_load_lds((gvoid*)(g), (lvoid*)(l), 16, 0, 0)

__device__ __forceinline__ unsigned short f2bf(float f) {
    unsigned u = __float_as_uint(f);
    return (unsigned short)((u + 0x7FFFu + ((u >> 16) & 1u)) >> 16);
}
__device__ __forceinline__ float bf2f(unsigned short h) {
    return __uint_as_float(((unsigned)h) << 16);
}

// ---------------------------------------------------------------------------
// bf16 MFMA GEMM: C[M x N] = act(A[M x K](bf16) * B[K x N] + bias)
// B supplied TRANSPOSED: Bt[N][K] bf16. 128x128 tile, BK=32, 256 threads,
// global_load_lds(16B) staging (m97 structure). blockIdx.z batches with
// element strides sA/sB/sC (0 for unbatched).
// ACT: 0 none, 1 relu, 2 gelu(exact). OUTM: 1 = bf16 C only, 2 = f32 + bf16.
// ---------------------------------------------------------------------------
template<int ACT, int OUTM>
__global__ __launch_bounds__(256) void gemm_bf16(
    const unsigned short* __restrict__ A, int lda,
    const unsigned short* __restrict__ Bt, int ldb,
    const float* __restrict__ bias,
    float* __restrict__ Cf, unsigned short* __restrict__ Cb,
    int ldc, int K, long sA, long sB, long sC)
{
    A  += (size_t)blockIdx.z * sA;
    Bt += (size_t)blockIdx.z * sB;
    if (OUTM == 2) Cf += (size_t)blockIdx.z * sC;
    Cb += (size_t)blockIdx.z * sC;

    __shared__ __attribute__((aligned(16))) unsigned short As[4096]; // 128 x 32
    __shared__ __attribute__((aligned(16))) unsigned short Bs[4096]; // 128 x 32 (n-major)
    const int t    = threadIdx.x;
    const int lane = t & 63;
    const int wave = t >> 6;
    const int wm = wave & 1, wn = wave >> 1;
    const int m0 = blockIdx.x * 128, n0 = blockIdx.y * 128;

    const int r0   = t >> 2;
    const int koff = (t & 3) * 8;
    const unsigned short* ga0 = A  + (size_t)(m0 + r0)      * lda + koff;
    const unsigned short* ga1 = A  + (size_t)(m0 + r0 + 64) * lda + koff;
    const unsigned short* gb0 = Bt + (size_t)(n0 + r0)      * ldb + koff;
    const unsigned short* gb1 = Bt + (size_t)(n0 + r0 + 64) * ldb + koff;
    unsigned short* la0 = As + t * 8;
    unsigned short* la1 = As + t * 8 + 2048;
    unsigned short* lb0 = Bs + t * 8;
    unsigned short* lb1 = Bs + t * 8 + 2048;

    f32x4 acc[4][4];
    #pragma unroll
    for (int i = 0; i < 4; ++i)
        #pragma unroll
        for (int j = 0; j < 4; ++j) acc[i][j] = (f32x4)0.0f;

    const int fm = lane & 15;
    const int fq = (lane >> 4) * 8;
    const int arow = (wm * 64 + fm) * 32 + fq;   // + i*512
    const int brow = (wn * 64 + fm) * 32 + fq;   // + j*512

    for (int k0 = 0; k0 < K; k0 += 32) {
        GLDS16(ga0 + k0, la0);
        GLDS16(ga1 + k0, la1);
        GLDS16(gb0 + k0, lb0);
        GLDS16(gb1 + k0, lb1);
        __syncthreads();
        bf16x8 af[4], bg[4];
        #pragma unroll
        for (int i = 0; i < 4; ++i) af[i] = *(const bf16x8*)(As + arow + i * 512);
        #pragma unroll
        for (int j = 0; j < 4; ++j) bg[j] = *(const bf16x8*)(Bs + brow + j * 512);
        #pragma unroll
        for (int i = 0; i < 4; ++i)
            #pragma unroll
            for (int j = 0; j < 4; ++j)
                acc[i][j] = __builtin_amdgcn_mfma_f32_16x16x32_bf16(
                    af[i], bg[j], acc[i][j], 0, 0, 0);
        __syncthreads();
    }

    const int cb  = n0 + wn * 64 + fm;
    const int rbs = m0 + wm * 64 + (lane >> 4) * 4;
    #pragma unroll
    for (int j = 0; j < 4; ++j) {
        const int n = cb + j * 16;
        const float bv = bias[n];
        #pragma unroll
        for (int i = 0; i < 4; ++i) {
            #pragma unroll
            for (int r = 0; r < 4; ++r) {
                float v = acc[i][j][r] + bv;
                if (ACT == 1) v = fmaxf(v, 0.0f);
                if (ACT == 2) v = 0.5f * v * (1.0f + erff(v * 0.7071067811865476f));
                const size_t off = (size_t)(rbs + i * 16 + r) * ldc + n;
                if (OUTM == 2) Cf[off] = v;
                Cb[off] = f2bf(v);
            }
        }
    }
}

// ---------------------------------------------------------------------------
// one-shot weight conversion: transpose to [N][K] bf16 + bias concat
// ---------------------------------------------------------------------------
#define CW_QKV  786432   // 4*768*256
#define CW_O   1048576   // + 4*256*256
#define CW_1   1572864   // + 4*512*256
#define CW_2   2097152   // + 4*256*512
#define CW_X   2129920   // + 256*128
#define CW_B   2132992   // + 4*768
__global__ __launch_bounds__(256) void conv_weights(
    const float* __restrict__ Wq, const float* __restrict__ Wk,
    const float* __restrict__ Wv, const float* __restrict__ Wo,
    const float* __restrict__ fw1, const float* __restrict__ fw2,
    const float* __restrict__ Wx_w,
    const float* __restrict__ bq, const float* __restrict__ bk,
    const float* __restrict__ bv,
    unsigned short* __restrict__ wqkv_t, unsigned short* __restrict__ wo_t,
    unsigned short* __restrict__ w1_t, unsigned short* __restrict__ w2_t,
    unsigned short* __restrict__ wx_bf, float* __restrict__ bqkv)
{
    const int e = blockIdx.x * 256 + threadIdx.x;
    if (e < CW_QKV) {
        const int i = e / 196608, r = e % 196608;
        const int n = r / 256, k = r % 256;
        const float* src = (n < 256) ? Wq : (n < 512) ? Wk : Wv;
        wqkv_t[e] = f2bf(src[((size_t)i * 256 + k) * 256 + (n & 255)]);
    } else if (e < CW_O) {
        const int r = e - CW_QKV;
        const int i = r / 65536, rr = r % 65536, n = rr / 256, k = rr % 256;
        wo_t[r] = f2bf(Wo[((size_t)i * 256 + k) * 256 + n]);
    } else if (e < CW_1) {
        const int r = e - CW_O;
        const int i = r / 131072, rr = r % 131072, n = rr / 256, k = rr % 256;
        w1_t[r] = f2bf(fw1[((size_t)i * 256 + k) * 512 + n]);
    } else if (e < CW_2) {
        const int r = e - CW_1;
        const int i = r / 131072, rr = r % 131072, n = rr / 512, k = rr % 512;
        w2_t[r] = f2bf(fw2[((size_t)i * 512 + k) * 256 + n]);
    } else if (e < CW_X) {
        const int r = e - CW_2;
        wx_bf[r] = f2bf(Wx_w[r]);     // Wx_w [out][in] is already B^T layout
    } else if (e < CW_B) {
        const int r = e - CW_X;
        const int i = r / 768, j = r % 768;
        const float v = (j < 256) ? bq[i * 256 + j]
                      : (j < 512) ? bk[i * 256 + j - 256]
                                  : bv[i * 256 + j - 512];
        bqkv[r] = v;
    }
}

// ---------------------------------------------------------------------------
// x [B][CIN][NTOK] f32 -> xbf [(b,n)][CIN] bf16, LDS 32x32 tile transpose.
// ---------------------------------------------------------------------------
__global__ __launch_bounds__(256) void conv_x(
    const float* __restrict__ x, unsigned short* __restrict__ xbf)
{
    __shared__ float tile[32][33];
    const int n0 = blockIdx.x * 32;
    const int c0 = blockIdx.y * 32;
    const int b  = blockIdx.z;
    const int t = threadIdx.x;
    const int tn = t & 31, tc = t >> 5;
    #pragma unroll
    for (int p = 0; p < 4; ++p)
        tile[tc + p * 8][tn] =
            x[((size_t)(b * CIN + c0 + tc + p * 8)) * NTOK + n0 + tn];
    __syncthreads();
    const int cc = t & 31, nr = t >> 5;
    #pragma unroll
    for (int p = 0; p < 4; ++p)
        xbf[((size_t)(b * NTOK + n0 + nr + p * 8)) * CIN + c0 + cc] =
            f2bf(tile[cc][nr + p * 8]);
}

// ---------------------------------------------------------------------------
// q softmax over dk=32, in place on the q-slot of qkv. 8 bf16 per lane.
// ---------------------------------------------------------------------------
__global__ __launch_bounds__(256) void qsm_kernel(unsigned short* __restrict__ qkv)
{
    const int g = blockIdx.x * 256 + threadIdx.x;   // < MTOT*32
    const int row = g >> 5;
    const int cg  = g & 31;                          // 8-channel chunk
    unsigned short* p = qkv + (size_t)row * 768 + cg * 8;
    uint4 raw = *(const uint4*)p;
    unsigned short* rp = (unsigned short*)&raw;
    float v[8];
    #pragma unroll
    for (int j = 0; j < 8; ++j) v[j] = bf2f(rp[j]);
    float m = v[0];
    #pragma unroll
    for (int j = 1; j < 8; ++j) m = fmaxf(m, v[j]);
    m = fmaxf(m, __shfl_xor(m, 1, 64));
    m = fmaxf(m, __shfl_xor(m, 2, 64));
    float s = 0.0f;
    #pragma unroll
    for (int j = 0; j < 8; ++j) { v[j] = __expf(v[j] - m); s += v[j]; }
    s += __shfl_xor(s, 1, 64);
    s += __shfl_xor(s, 2, 64);
    const float r = 1.0f / s;
    #pragma unroll
    for (int j = 0; j < 8; ++j) rp[j] = f2bf(v[j] * r);
    *(uint4*)p = raw;
}

// ---------------------------------------------------------------------------
// ctx_unnorm[b][h][d][e] = sum_n exp(k[n][d]) * v[n][e]  (no max shift;
// |k| << 80). Also Sk[b][ch] = sum_n exp(k[n][ch]) via atomics.
// grid (108, NHEAD, B), block 256. Chunk = 128 tokens.
// LDS: exp(k), v staged f32 with row stride 36 (16B-aligned, uniform
// quad-bank spread). Compute: thread=(d-quad,e-quad), 2 b128 reads -> 16 FMA
// per token. Cross-wave combine via LDS (stride 20), 16 atomics / block.
// ctx and Sk must be pre-zeroed.
// ---------------------------------------------------------------------------
#define CTX_S 36
__global__ __launch_bounds__(256) void ctx_kernel(
    const unsigned short* __restrict__ qkv,
    float* __restrict__ ctx, float* __restrict__ Sk)
{
    const int chunk = blockIdx.x, h = blockIdx.y, b = blockIdx.z;
    const int n0 = chunk * 128;
    const int t = threadIdx.x;
    __shared__ __attribute__((aligned(16))) float lds[2 * 128 * CTX_S];
    float* keS = lds;
    float* veS = lds + 128 * CTX_S;

    // ---- staging: 128 tokens x 32 ch (k and v), exp on k ----
    const unsigned short* kb =
        qkv + ((size_t)(b * NTOK + n0)) * 768 + 256 + h * 32;
    #pragma unroll
    for (int p = 0; p < 2; ++p) {
        const int idx = p * 256 + t;
        const int tl = idx >> 2, cg = idx & 3;
        const unsigned short* kp = kb + (size_t)tl * 768 + cg * 8;
        const uint4 kr = *(const uint4*)kp;
        const uint4 vr = *(const uint4*)(kp + 256);   // v-slot (+512 B)
        const unsigned short* ks = (const unsigned short*)&kr;
        const unsigned short* vs = (const unsigned short*)&vr;
        float ke[8], ve[8];
        #pragma unroll
        for (int j = 0; j < 8; ++j) {
            ke[j] = __expf(bf2f(ks[j]));
            ve[j] = bf2f(vs[j]);
        }
        float* kd = keS + tl * CTX_S + cg * 8;
        float* vd = veS + tl * CTX_S + cg * 8;
        *(float4*)(kd)     = *(float4*)(ke);
        *(float4*)(kd + 4) = *(float4*)(ke + 4);
        *(float4*)(vd)     = *(float4*)(ve);
        *(float4*)(vd + 4) = *(float4*)(ve + 4);
    }
    __syncthreads();

    // ---- compute: wave w covers tokens [w*32, w*32+32) ----
    const int w = t >> 6, l = t & 63;
    const int dq = l >> 3, eq = l & 7;
    float acc[4][4] = {};
    float ssum[4] = {0, 0, 0, 0};
    #pragma unroll 4
    for (int tok = 0; tok < 32; ++tok) {
        const int tl = w * 32 + tok;
        const float4 kv = *(const float4*)(keS + tl * CTX_S + dq * 4);
        const float4 vv = *(const float4*)(veS + tl * CTX_S + eq * 4);
        const float ka[4] = {kv.x, kv.y, kv.z, kv.w};
        const float va[4] = {vv.x, vv.y, vv.z, vv.w};
        #pragma unroll
        for (int i = 0; i < 4; ++i)
            #pragma unroll
            for (int j = 0; j < 4; ++j)
                acc[i][j] += ka[i] * va[j];
        if (eq == 0) {
            #pragma unroll
            for (int i = 0; i < 4; ++i) ssum[i] += ka[i];
        }
    }
    if (eq == 0) {
        #pragma unroll
        for (int i = 0; i < 4; ++i)
            atomicAdd(&Sk[b * 256 + h * 32 + dq * 4 + i], ssum[i]);
    }

    // ---- cross-wave reduce (reuse lds; stride 20 => uniform quad-banks) ----
    __syncthreads();
    float* red = lds;
    {
        float* rp = red + (size_t)(w * 64 + l) * 20;
        #pragma unroll
        for (int i = 0; i < 4; ++i)
            *(float4*)(rp + i * 4) = *(float4*)(acc[i]);
    }
    __syncthreads();
    if (t < 64) {
        float r[16];
        #pragma unroll
        for (int i = 0; i < 16; ++i) r[i] = 0.0f;
        #pragma unroll
        for (int w2 = 0; w2 < 4; ++w2) {
            const float* rp = red + (size_t)(w2 * 64 + t) * 20;
            #pragma unroll
            for (int i = 0; i < 4; ++i) {
                const float4 v4 = *(const float4*)(rp + i * 4);
                r[i * 4 + 0] += v4.x; r[i * 4 + 1] += v4.y;
                r[i * 4 + 2] += v4.z; r[i * 4 + 3] += v4.w;
            }
        }
        const int dq2 = t >> 3, eq2 = t & 7;
        float* cp = ctx + (size_t)(b * 8 + h) * 1024;
        #pragma unroll
        for (int i = 0; i < 4; ++i)
            #pragma unroll
            for (int j = 0; j < 4; ++j)
                atomicAdd(&cp[(dq2 * 4 + i) * 32 + eq2 * 4 + j], r[i * 4 + j]);
    }
}

// ---------------------------------------------------------------------------
// W'[b][n][h*32+d] = (1/sqrt(dk)) * (1/Sk[d]) * sum_e ctx[b][h][d][e] * Wo[h*32+e][n]
// ---------------------------------------------------------------------------
__global__ __launch_bounds__(256) void ctxwo_kernel(
    const float* __restrict__ ctx, const float* __restrict__ Sk,
    const unsigned short* __restrict__ wo_t, unsigned short* __restrict__ wp)
{
    const int h = blockIdx.x, b = blockIdx.y;
    const int n = threadIdx.x;
    __shared__ float cl[1024];
    __shared__ float sdk[32];
    {
        const float* cp = ctx + (size_t)(b * 8 + h) * 1024;
        *(float4*)&cl[n * 4] = *(const float4*)&cp[n * 4];
    }
    if (n < 32) sdk[n] = 0.17677669529663687f / Sk[b * 256 + h * 32 + n];
    __syncthreads();
    float w[32];
    const unsigned short* wop = wo_t + (size_t)n * 256 + h * 32;
    #pragma unroll
    for (int e = 0; e < 32; ++e) w[e] = bf2f(wop[e]);
    unsigned short outv[32];
    #pragma unroll
    for (int d = 0; d < 32; ++d) {
        float acc = 0.0f;
        #pragma unroll
        for (int e = 0; e < 32; ++e) acc += cl[d * 32 + e] * w[e];
        outv[d] = f2bf(acc * sdk[d]);
    }
    unsigned short* op = wp + (size_t)b * 65536 + (size_t)n * 256 + h * 32;
    #pragma unroll
    for (int d = 0; d < 32; d += 8)
        *(uint4*)(op + d) = *(uint4*)(outv + d);
}

// ---------------------------------------------------------------------------
// t = LayerNorm(t + add(bf16)); writes t f32 in place (+ optional bf16 copy)
// ---------------------------------------------------------------------------
template<int WB>
__global__ __launch_bounds__(256) void ln_kernel(
    float* __restrict__ t, const unsigned short* __restrict__ add,
    const float* __restrict__ g, const float* __restrict__ bta,
    unsigned short* __restrict__ tbf)
{
    const int row = blockIdx.x;
    const int c = threadIdx.x;
    const int lane = c & 63, wave = c >> 6;
    const size_t off = (size_t)row * 256 + c;
    const float v = t[off] + bf2f(add[off]);
    __shared__ float red[8];
    float s = v;
    #pragma unroll
    for (int o = 32; o; o >>= 1) s += __shfl_xor(s, o, 64);
    if (lane == 0) red[wave] = s;
    __syncthreads();
    const float mu = (red[0] + red[1] + red[2] + red[3]) * (1.0f / 256.0f);
    const float dv = v - mu;
    float s2 = dv * dv;
    #pragma unroll
    for (int o = 32; o; o >>= 1) s2 += __shfl_xor(s2, o, 64);
    if (lane == 0) red[wave + 4] = s2;
    __syncthreads();
    const float var = (red[4] + red[5] + red[6] + red[7]) * (1.0f / 256.0f);
    const float o = dv * rsqrtf(var + 1e-6f) * g[c] + bta[c];
    t[off] = o;
    if (WB) tbf[off] = f2bf(o);
}

// ---------------------------------------------------------------------------
// depthwise 3x3x3 conv + residual, register-resident weights + sliding window.
// ---------------------------------------------------------------------------
template<int WB>
__global__ __launch_bounds__(256) void posconv_kernel(
    const float* __restrict__ tin, const float* __restrict__ pw,
    const float* __restrict__ pb, float* __restrict__ outp,
    unsigned short* __restrict__ tbfp)
{
    const int hw = blockIdx.x;            // 0..575
    const int b  = blockIdx.y;
    const int hh = hw / 24, ww = hw % 24;
    const int c  = threadIdx.x;

    float w[27];
    #pragma unroll
    for (int k = 0; k < 27; ++k) w[k] = pw[c * 27 + k];
    const float bias = pb[c];

    const float* base = tin + (size_t)b * NTOK * 256 + c;

    const float* colp[9];
    bool colok[9];
    #pragma unroll
    for (int dh = -1; dh <= 1; ++dh)
        #pragma unroll
        for (int dw = -1; dw <= 1; ++dw) {
            const int j = (dh + 1) * 3 + (dw + 1);
            const int h2 = hh + dh, w2 = ww + dw;
            colok[j] = ((unsigned)h2 < 24u) & ((unsigned)w2 < 24u);
            colp[j] = base + (size_t)((h2 * 24 + w2) * 24) * 256;
        }

    float win[9][3];
    #pragma unroll
    for (int j = 0; j < 9; ++j) {
        win[j][0] = 0.0f;
        win[j][1] = colok[j] ? colp[j][0] : 0.0f;
    }

    float* ob = outp + ((size_t)b * NTOK + (size_t)hw * 24) * 256 + c;
    unsigned short* tb = WB ? (tbfp + ((size_t)b * NTOK + (size_t)hw * 24) * 256 + c)
                            : (unsigned short*)nullptr;

    for (int d = 0; d < 24; ++d) {
        #pragma unroll
        for (int j = 0; j < 9; ++j)
            win[j][2] = (colok[j] && d < 23) ? colp[j][(d + 1) * 256] : 0.0f;

        float acc = bias + win[4][1];
        #pragma unroll
        for (int j = 0; j < 9; ++j) {
            acc += w[j * 3 + 0] * win[j][0];
            acc += w[j * 3 + 1] * win[j][1];
            acc += w[j * 3 + 2] * win[j][2];
        }
        ob[d * 256] = acc;
        if (WB) tb[d * 256] = f2bf(acc);

        #pragma unroll
        for (int j = 0; j < 9; ++j) { win[j][0] = win[j][1]; win[j][1] = win[j][2]; }
    }
}

// ---------------------------------------------------------------------------
// final transpose: t [MTOT][256] f32 -> out [B][256][NTOK] (LDS tiled)
// ---------------------------------------------------------------------------
__global__ __launch_bounds__(256) void tr_out(
    const float* __restrict__ tin, float* __restrict__ outp)
{
    __shared__ float tile[32][33];
    const int m0 = blockIdx.x * 32;
    const int c0 = blockIdx.y * 32;
    const int t = threadIdx.x;
    const int tc = t & 31, tr = t >> 5;
    #pragma unroll
    for (int r = 0; r < 4; ++r)
        tile[tr + r * 8][tc] = tin[(size_t)(m0 + tr + r * 8) * 256 + c0 + tc];
    __syncthreads();
    const int b = (m0 >= NTOK) ? 1 : 0;
    const int n0 = m0 - b * NTOK;
    #pragma unroll
    for (int r = 0; r < 4; ++r)
        outp[((size_t)b * 256 + c0 + tr + r * 8) * NTOK + n0 + tc] = tile[tc][tr + r * 8];
}

// ---------------------------------------------------------------------------
// launch
// ---------------------------------------------------------------------------
extern "C" void kernel_launch(void* const* d_in, const int* in_sizes, int n_in,
                              void* d_out, int out_size, void* d_ws, size_t ws_size,
                              hipStream_t stream)
{
    (void)in_sizes; (void)n_in; (void)out_size; (void)ws_size;
    const float* x     = (const float*)d_in[0];
    const float* Wx_w  = (const float*)d_in[1];
    const float* Wx_b  = (const float*)d_in[2];
    const float* Wq    = (const float*)d_in[3];
    const float* bq    = (const float*)d_in[4];
    const float* Wk    = (const float*)d_in[5];
    const float* bk    = (const float*)d_in[6];
    const float* Wv    = (const float*)d_in[7];
    const float* bv    = (const float*)d_in[8];
    const float* Wo    = (const float*)d_in[9];
    const float* bo    = (const float*)d_in[10];
    const float* ln1_g = (const float*)d_in[11];
    const float* ln1_b = (const float*)d_in[12];
    const float* ln2_g = (const float*)d_in[13];
    const float* ln2_b = (const float*)d_in[14];
    const float* fw1   = (const float*)d_in[15];
    const float* fb1   = (const float*)d_in[16];
    const float* fw2   = (const float*)d_in[17];
    const float* fb2   = (const float*)d_in[18];
    const float* pw    = (const float*)d_in[19];
    const float* pb    = (const float*)d_in[20];
    float* out = (float*)d_out;

    char* p = (char*)d_ws;
    float* tA            = (float*)p;          p += (size_t)MTOT * 256 * 4;
    float* tB            = (float*)p;          p += (size_t)MTOT * 256 * 4;
    unsigned short* tbf  = (unsigned short*)p; p += (size_t)MTOT * 256 * 2;
    unsigned short* qkv  = (unsigned short*)p; p += (size_t)MTOT * 768 * 2;
    unsigned short* hbf  = (unsigned short*)p; p += (size_t)MTOT * 512 * 2;
    unsigned short* ob   = (unsigned short*)p; p += (size_t)MTOT * 256 * 2;
    unsigned short* xbf  = (unsigned short*)p; p += (size_t)MTOT * 128 * 2;
    unsigned short* wqkv_t = (unsigned short*)p; p += (size_t)786432 * 2;
    unsigned short* wo_t   = (unsigned short*)p; p += (size_t)262144 * 2;
    unsigned short* w1_t   = (unsigned short*)p; p += (size_t)524288 * 2;
    unsigned short* w2_t   = (unsigned short*)p; p += (size_t)524288 * 2;
    unsigned short* wx_bf  = (unsigned short*)p; p += (size_t)32768 * 2;
    unsigned short* wp     = (unsigned short*)p; p += (size_t)BATCH * 65536 * 2;
    float* bqkv = (float*)p; p += 3072 * 4;
    float* ctx  = (float*)p; p += 16384 * 4;   // ctx + Sk contiguous (one memset)
    float* Sk   = (float*)p; p += 512 * 4;

    hipLaunchKernelGGL(conv_weights, dim3(8333), dim3(256), 0, stream,
                       Wq, Wk, Wv, Wo, fw1, fw2, Wx_w, bq, bk, bv,
                       wqkv_t, wo_t, w1_t, w2_t, wx_bf, bqkv);
    hipLaunchKernelGGL(conv_x, dim3(NTOK / 32, CIN / 32, BATCH), dim3(256), 0, stream,
                       x, xbf);

    // input 1x1x1 conv + relu -> tA f32 + tbf bf16
    hipLaunchKernelGGL((gemm_bf16<1, 2>), dim3(216, 2, 1), dim3(256), 0, stream,
                       xbf, CIN, wx_bf, CIN, Wx_b, tA, tbf, 256, CIN,
                       (long)0, (long)0, (long)0);

    for (int i = 0; i < NLAYERS; ++i) {
        float* tin  = (i & 1) ? tB : tA;
        float* tout = (i & 1) ? tA : tB;

        // fused QKV: [M,256] x [256,768]
        hipLaunchKernelGGL((gemm_bf16<0, 1>), dim3(216, 6, 1), dim3(256), 0, stream,
                           tbf, 256, wqkv_t + (size_t)i * 196608, 256,
                           bqkv + i * 768, nullptr, qkv, 768, 256,
                           (long)0, (long)0, (long)0);

        // ctx (+ Sk) accumulate; no max-shift needed (|k| << 80)
        hipMemsetAsync(ctx, 0, (16384 + 512) * sizeof(float), stream);
        hipLaunchKernelGGL(ctx_kernel, dim3(108, NHEAD, BATCH), dim3(256), 0, stream,
                           qkv, ctx, Sk);

        // q softmax in place + W' = (ctx/Sk) @ Wo (per batch)
        hipLaunchKernelGGL(qsm_kernel, dim3(3456), dim3(256), 0, stream, qkv);
        hipLaunchKernelGGL(ctxwo_kernel, dim3(NHEAD, BATCH), dim3(256), 0, stream,
                           ctx, Sk, wo_t + (size_t)i * 65536, wp);

        // o_proj = qs @ W' + bo  (batched over z)
        hipLaunchKernelGGL((gemm_bf16<0, 1>), dim3(108, 2, BATCH), dim3(256), 0, stream,
                           qkv, 768, wp, 256, bo + i * 256, nullptr, ob, 256, 256,
                           (long)NTOK * 768, (long)65536, (long)NTOK * 256);

        hipLaunchKernelGGL((ln_kernel<1>), dim3(MTOT), dim3(256), 0, stream,
                           tin, ob, ln1_g + i * 256, ln1_b + i * 256, tbf);

        // FFN
        hipLaunchKernelGGL((gemm_bf16<2, 1>), dim3(216, 4, 1), dim3(256), 0, stream,
                           tbf, 256, w1_t + (size_t)i * 131072, 256,
                           fb1 + i * 512, nullptr, hbf, 512, 256,
                           (long)0, (long)0, (long)0);
        hipLaunchKernelGGL((gemm_bf16<0, 1>), dim3(216, 2, 1), dim3(256), 0, stream,
                           hbf, 512, w2_t + (size_t)i * 131072, 512,
                           fb2 + i * 256, nullptr, ob, 256, 512,
                           (long)0, (long)0, (long)0);
        hipLaunchKernelGGL((ln_kernel<0>), dim3(MTOT), dim3(256), 0, stream,
                           tin, ob, ln2_g + i * 256, ln2_b + i * 256, nullptr);

        // depthwise conv + residual -> tout f32 (+ tbf bf16 except last layer)
        if (i < NLAYERS - 1)
            hipLaunchKernelGGL((posconv_kernel<1>), dim3(576, BATCH), dim3(256), 0, stream,
                               tin, pw + (size_t)i * 6912, pb + i * 256, tout, tbf);
        else
            hipLaunchKernelGGL((posconv_kernel<0>), dim3(576, BATCH), dim3(256), 0, stream,
                               tin, pw + (size_t)i * 6912, pb + i * 256, tout, nullptr);
    }

    // layer 3 wrote tA
    hipLaunchKernelGGL(tr_out, dim3(MTOT / 32, 8), dim3(256), 0, stream, tA, out);
}

// Round 7
// 904.964 us; speedup vs baseline: 1.3777x; 1.3777x over previous
//
#include <hip/hip_runtime.h>
#include <math.h>

#define NTOK 13824            // 24*24*24
#define MTOT 27648            // B*NTOK
#define BATCH 2
#define CIN 128
#define DMODEL 256
#define NHEAD 8
#define NLAYERS 4
#define DFF 512
#define NSPLIT 27
#define KVHALF ((size_t)BATCH * 256 * NTOK)

typedef float f32x4 __attribute__((ext_vector_type(4)));
typedef __bf16 bf16x8 __attribute__((ext_vector_type(8)));
typedef __attribute__((address_space(1))) void gvoid;
typedef __attribute__((address_space(3))) void lvoid;

// async global->LDS, 16B per lane. LDS dest must be uniform-base + lane*16.
#define GLDS16(g, l) __builtin_amdgcn_global_load_lds((gvoid*)(g), (lvoid*)(l), 16, 0, 0)

__device__ __forceinline__ unsigned short f2bf(float f) {
    unsigned u = __float_as_uint(f);
    return (unsigned short)((u + 0x7FFFu + ((u >> 16) & 1u)) >> 16);
}
__device__ __forceinline__ float bf2f(unsigned short h) {
    return __uint_as_float(((unsigned)h) << 16);
}

// ---------------------------------------------------------------------------
// bf16 MFMA GEMM: C[M x N] = act(A[M x K](bf16) * B[K x N] + bias)
// B supplied TRANSPOSED: Bt[N][K] bf16. 128x128 tile, BK=32, 256 threads,
// global_load_lds(16B) staging (m97 structure). blockIdx.z batches with
// element strides sA/sB/sC (0 for unbatched).
// ACT: 0 none, 1 relu, 2 gelu(exact). OUTM: 1 = bf16 C only, 2 = f32 + bf16.
// ---------------------------------------------------------------------------
template<int ACT, int OUTM>
__global__ __launch_bounds__(256) void gemm_bf16(
    const unsigned short* __restrict__ A, int lda,
    const unsigned short* __restrict__ Bt, int ldb,
    const float* __restrict__ bias,
    float* __restrict__ Cf, unsigned short* __restrict__ Cb,
    int ldc, int K, long sA, long sB, long sC)
{
    A  += (size_t)blockIdx.z * sA;
    Bt += (size_t)blockIdx.z * sB;
    if (OUTM == 2) Cf += (size_t)blockIdx.z * sC;
    Cb += (size_t)blockIdx.z * sC;

    __shared__ __attribute__((aligned(16))) unsigned short As[4096]; // 128 x 32
    __shared__ __attribute__((aligned(16))) unsigned short Bs[4096]; // 128 x 32 (n-major)
    const int t    = threadIdx.x;
    const int lane = t & 63;
    const int wave = t >> 6;
    const int wm = wave & 1, wn = wave >> 1;
    const int m0 = blockIdx.x * 128, n0 = blockIdx.y * 128;

    const int r0   = t >> 2;
    const int koff = (t & 3) * 8;
    const unsigned short* ga0 = A  + (size_t)(m0 + r0)      * lda + koff;
    const unsigned short* ga1 = A  + (size_t)(m0 + r0 + 64) * lda + koff;
    const unsigned short* gb0 = Bt + (size_t)(n0 + r0)      * ldb + koff;
    const unsigned short* gb1 = Bt + (size_t)(n0 + r0 + 64) * ldb + koff;
    unsigned short* la0 = As + t * 8;
    unsigned short* la1 = As + t * 8 + 2048;
    unsigned short* lb0 = Bs + t * 8;
    unsigned short* lb1 = Bs + t * 8 + 2048;

    f32x4 acc[4][4];
    #pragma unroll
    for (int i = 0; i < 4; ++i)
        #pragma unroll
        for (int j = 0; j < 4; ++j) acc[i][j] = (f32x4)0.0f;

    const int fm = lane & 15;
    const int fq = (lane >> 4) * 8;
    const int arow = (wm * 64 + fm) * 32 + fq;   // + i*512
    const int brow = (wn * 64 + fm) * 32 + fq;   // + j*512

    for (int k0 = 0; k0 < K; k0 += 32) {
        GLDS16(ga0 + k0, la0);
        GLDS16(ga1 + k0, la1);
        GLDS16(gb0 + k0, lb0);
        GLDS16(gb1 + k0, lb1);
        __syncthreads();
        bf16x8 af[4], bg[4];
        #pragma unroll
        for (int i = 0; i < 4; ++i) af[i] = *(const bf16x8*)(As + arow + i * 512);
        #pragma unroll
        for (int j = 0; j < 4; ++j) bg[j] = *(const bf16x8*)(Bs + brow + j * 512);
        #pragma unroll
        for (int i = 0; i < 4; ++i)
            #pragma unroll
            for (int j = 0; j < 4; ++j)
                acc[i][j] = __builtin_amdgcn_mfma_f32_16x16x32_bf16(
                    af[i], bg[j], acc[i][j], 0, 0, 0);
        __syncthreads();
    }

    const int cb  = n0 + wn * 64 + fm;
    const int rbs = m0 + wm * 64 + (lane >> 4) * 4;
    #pragma unroll
    for (int j = 0; j < 4; ++j) {
        const int n = cb + j * 16;
        const float bv = bias[n];
        #pragma unroll
        for (int i = 0; i < 4; ++i) {
            #pragma unroll
            for (int r = 0; r < 4; ++r) {
                float v = acc[i][j][r] + bv;
                if (ACT == 1) v = fmaxf(v, 0.0f);
                if (ACT == 2) v = 0.5f * v * (1.0f + erff(v * 0.7071067811865476f));
                const size_t off = (size_t)(rbs + i * 16 + r) * ldc + n;
                if (OUTM == 2) Cf[off] = v;
                Cb[off] = f2bf(v);
            }
        }
    }
}

// ---------------------------------------------------------------------------
// one-shot weight conversion: transpose to [N][K] bf16 + bias concat
// ---------------------------------------------------------------------------
#define CW_QKV  786432   // 4*768*256
#define CW_O   1048576   // + 4*256*256
#define CW_1   1572864   // + 4*512*256
#define CW_2   2097152   // + 4*256*512
#define CW_X   2129920   // + 256*128
#define CW_B   2132992   // + 4*768
__global__ __launch_bounds__(256) void conv_weights(
    const float* __restrict__ Wq, const float* __restrict__ Wk,
    const float* __restrict__ Wv, const float* __restrict__ Wo,
    const float* __restrict__ fw1, const float* __restrict__ fw2,
    const float* __restrict__ Wx_w,
    const float* __restrict__ bq, const float* __restrict__ bk,
    const float* __restrict__ bv,
    unsigned short* __restrict__ wqkv_t, unsigned short* __restrict__ wo_t,
    unsigned short* __restrict__ w1_t, unsigned short* __restrict__ w2_t,
    unsigned short* __restrict__ wx_bf, float* __restrict__ bqkv)
{
    const int e = blockIdx.x * 256 + threadIdx.x;
    if (e < CW_QKV) {
        const int i = e / 196608, r = e % 196608;
        const int n = r / 256, k = r % 256;
        const float* src = (n < 256) ? Wq : (n < 512) ? Wk : Wv;
        wqkv_t[e] = f2bf(src[((size_t)i * 256 + k) * 256 + (n & 255)]);
    } else if (e < CW_O) {
        const int r = e - CW_QKV;
        const int i = r / 65536, rr = r % 65536, n = rr / 256, k = rr % 256;
        wo_t[r] = f2bf(Wo[((size_t)i * 256 + k) * 256 + n]);
    } else if (e < CW_1) {
        const int r = e - CW_O;
        const int i = r / 131072, rr = r % 131072, n = rr / 256, k = rr % 256;
        w1_t[r] = f2bf(fw1[((size_t)i * 256 + k) * 512 + n]);
    } else if (e < CW_2) {
        const int r = e - CW_1;
        const int i = r / 131072, rr = r % 131072, n = rr / 512, k = rr % 512;
        w2_t[r] = f2bf(fw2[((size_t)i * 512 + k) * 256 + n]);
    } else if (e < CW_X) {
        const int r = e - CW_2;
        wx_bf[r] = f2bf(Wx_w[r]);     // Wx_w [out][in] is already B^T layout
    } else if (e < CW_B) {
        const int r = e - CW_X;
        const int i = r / 768, j = r % 768;
        const float v = (j < 256) ? bq[i * 256 + j]
                      : (j < 512) ? bk[i * 256 + j - 256]
                                  : bv[i * 256 + j - 512];
        bqkv[r] = v;
    }
}

// ---------------------------------------------------------------------------
// x [B][CIN][NTOK] f32 -> xbf [(b,n)][CIN] bf16, LDS 32x32 tile transpose.
// ---------------------------------------------------------------------------
__global__ __launch_bounds__(256) void conv_x(
    const float* __restrict__ x, unsigned short* __restrict__ xbf)
{
    __shared__ float tile[32][33];
    const int n0 = blockIdx.x * 32;
    const int c0 = blockIdx.y * 32;
    const int b  = blockIdx.z;
    const int t = threadIdx.x;
    const int tn = t & 31, tc = t >> 5;
    #pragma unroll
    for (int p = 0; p < 4; ++p)
        tile[tc + p * 8][tn] =
            x[((size_t)(b * CIN + c0 + tc + p * 8)) * NTOK + n0 + tn];
    __syncthreads();
    const int cc = t & 31, nr = t >> 5;
    #pragma unroll
    for (int p = 0; p < 4; ++p)
        xbf[((size_t)(b * NTOK + n0 + nr + p * 8)) * CIN + c0 + cc] =
            f2bf(tile[cc][nr + p * 8]);
}

// ---------------------------------------------------------------------------
// q softmax over dk=32, in place on the q-slot of qkv. 8 bf16 per lane.
// ---------------------------------------------------------------------------
__global__ __launch_bounds__(256) void qsm_kernel(unsigned short* __restrict__ qkv)
{
    const int g = blockIdx.x * 256 + threadIdx.x;   // < MTOT*32
    const int row = g >> 5;
    const int cg  = g & 31;                          // 8-channel chunk
    unsigned short* p = qkv + (size_t)row * 768 + cg * 8;
    uint4 raw = *(const uint4*)p;
    unsigned short* rp = (unsigned short*)&raw;
    float v[8];
    #pragma unroll
    for (int j = 0; j < 8; ++j) v[j] = bf2f(rp[j]);
    float m = v[0];
    #pragma unroll
    for (int j = 1; j < 8; ++j) m = fmaxf(m, v[j]);
    m = fmaxf(m, __shfl_xor(m, 1, 64));
    m = fmaxf(m, __shfl_xor(m, 2, 64));
    float s = 0.0f;
    #pragma unroll
    for (int j = 0; j < 8; ++j) { v[j] = __expf(v[j] - m); s += v[j]; }
    s += __shfl_xor(s, 1, 64);
    s += __shfl_xor(s, 2, 64);
    const float r = 1.0f / s;
    #pragma unroll
    for (int j = 0; j < 8; ++j) rp[j] = f2bf(v[j] * r);
    *(uint4*)p = raw;
}

// ---------------------------------------------------------------------------
// kvt: qkv k,v slots -> expkT/vT [b][ch][tok] bf16 (exp applied to k).
// grid (NTOK/64, NHEAD, B), block 256. LDS tile, coalesced both sides.
// kvT layout: [0, KVHALF) = expkT, [KVHALF, 2*KVHALF) = vT; row = b*256+ch.
// ---------------------------------------------------------------------------
__global__ __launch_bounds__(256) void kvt_kernel(
    const unsigned short* __restrict__ qkv, unsigned short* __restrict__ kvT)
{
    const int nb = blockIdx.x, h = blockIdx.y, b = blockIdx.z;
    const int n0 = nb * 64;
    const int t = threadIdx.x;
    __shared__ __attribute__((aligned(16))) unsigned short LT[64 * 72];
    const int tl = t >> 2, cg = t & 3;
    const unsigned short* src =
        qkv + ((size_t)(b * NTOK + n0 + tl)) * 768 + 256 + h * 32 + cg * 8;
    const uint4 kr = *(const uint4*)src;
    const uint4 vr = *(const uint4*)(src + 256);
    const unsigned short* ks = (const unsigned short*)&kr;
    const unsigned short* vs = (const unsigned short*)&vr;
    #pragma unroll
    for (int j = 0; j < 8; ++j) {
        const int ch = cg * 8 + j;
        LT[ch * 72 + tl]        = f2bf(__expf(bf2f(ks[j])));
        LT[(32 + ch) * 72 + tl] = vs[j];
    }
    __syncthreads();
    #pragma unroll
    for (int it = 0; it < 2; ++it) {
        const int idx = it * 256 + t;       // 0..511
        const int row = idx >> 3, seg = idx & 7;
        const uint4 val = *(const uint4*)(LT + row * 72 + seg * 8);
        const int ch = row & 31;
        const size_t dst = ((row >= 32) ? KVHALF : (size_t)0)
                         + ((size_t)(b * 256 + h * 32 + ch)) * NTOK + n0 + seg * 8;
        *(uint4*)(kvT + dst) = val;
    }
}

// ---------------------------------------------------------------------------
// ctx via MFMA, split-K, NO atomics.
// grid (NSPLIT, NHEAD, B), block 256 (4 waves). Each wave: 128 tokens,
// 16x16x32 MFMA, A = expkT rows (d), B = vT rows (e) -- direct global
// bf16x8 fragment loads (contiguous). Sk partials from A-frag sums.
// Outputs ctxp[s][b*8+h][1024], skp[s][b*256+ch].
// ---------------------------------------------------------------------------
__global__ __launch_bounds__(256) void ctx_mfma(
    const unsigned short* __restrict__ kvT,
    float* __restrict__ ctxp, float* __restrict__ skp)
{
    const int s = blockIdx.x, h = blockIdx.y, b = blockIdx.z;
    const int t = threadIdx.x, w = t >> 6, l = t & 63;
    const int fm = l & 15, fq = (l >> 4) * 8;
    const size_t rowA = (size_t)(b * 256 + h * 32 + fm) * NTOK;
    const int n0 = s * 512 + w * 128 + fq;
    const unsigned short* pa = kvT + rowA + n0;
    const unsigned short* pb = kvT + KVHALF + rowA + n0;

    f32x4 acc[2][2];
    #pragma unroll
    for (int x = 0; x < 2; ++x)
        #pragma unroll
        for (int y = 0; y < 2; ++y) acc[x][y] = (f32x4)0.0f;
    float ss0 = 0.0f, ss1 = 0.0f;

    #pragma unroll
    for (int step = 0; step < 4; ++step) {
        const int ko = step * 32;
        const uint4 ra0 = *(const uint4*)(pa + ko);
        const uint4 ra1 = *(const uint4*)(pa + (size_t)16 * NTOK + ko);
        const uint4 rb0 = *(const uint4*)(pb + ko);
        const uint4 rb1 = *(const uint4*)(pb + (size_t)16 * NTOK + ko);
        const bf16x8 a0 = *(const bf16x8*)&ra0;
        const bf16x8 a1 = *(const bf16x8*)&ra1;
        const bf16x8 b0 = *(const bf16x8*)&rb0;
        const bf16x8 b1 = *(const bf16x8*)&rb1;
        acc[0][0] = __builtin_amdgcn_mfma_f32_16x16x32_bf16(a0, b0, acc[0][0], 0, 0, 0);
        acc[0][1] = __builtin_amdgcn_mfma_f32_16x16x32_bf16(a0, b1, acc[0][1], 0, 0, 0);
        acc[1][0] = __builtin_amdgcn_mfma_f32_16x16x32_bf16(a1, b0, acc[1][0], 0, 0, 0);
        acc[1][1] = __builtin_amdgcn_mfma_f32_16x16x32_bf16(a1, b1, acc[1][1], 0, 0, 0);
        const unsigned short* u0 = (const unsigned short*)&ra0;
        const unsigned short* u1 = (const unsigned short*)&ra1;
        #pragma unroll
        for (int j = 0; j < 8; ++j) { ss0 += bf2f(u0[j]); ss1 += bf2f(u1[j]); }
    }

    // Sk: reduce over the 4 quads holding the same d
    ss0 += __shfl_xor(ss0, 16, 64); ss0 += __shfl_xor(ss0, 32, 64);
    ss1 += __shfl_xor(ss1, 16, 64); ss1 += __shfl_xor(ss1, 32, 64);
    __shared__ float skw[4][32];
    __shared__ float redc[4][32][33];
    if (l < 16) { skw[w][fm] = ss0; skw[w][16 + fm] = ss1; }

    // stage C tiles: row = x*16 + (l>>4)*4 + r, col = y*16 + fm
    const int rb4 = (l >> 4) * 4;
    #pragma unroll
    for (int x = 0; x < 2; ++x)
        #pragma unroll
        for (int y = 0; y < 2; ++y)
            #pragma unroll
            for (int r = 0; r < 4; ++r)
                redc[w][x * 16 + rb4 + r][y * 16 + fm] = acc[x][y][r];
    __syncthreads();

    if (t < 32)
        skp[(size_t)s * 512 + b * 256 + h * 32 + t] =
            skw[0][t] + skw[1][t] + skw[2][t] + skw[3][t];

    // 1024 outputs, 4 per thread
    const int e0 = t * 4;
    const int dd = e0 >> 5, c0 = e0 & 31;
    float4 o;
    o.x = redc[0][dd][c0+0] + redc[1][dd][c0+0] + redc[2][dd][c0+0] + redc[3][dd][c0+0];
    o.y = redc[0][dd][c0+1] + redc[1][dd][c0+1] + redc[2][dd][c0+1] + redc[3][dd][c0+1];
    o.z = redc[0][dd][c0+2] + redc[1][dd][c0+2] + redc[2][dd][c0+2] + redc[3][dd][c0+2];
    o.w = redc[0][dd][c0+3] + redc[1][dd][c0+3] + redc[2][dd][c0+3] + redc[3][dd][c0+3];
    *(float4*)(ctxp + ((size_t)s * 16 + b * 8 + h) * 1024 + e0) = o;
}

// reduce split-K partials: ctx[16][1024] and Sk[512]. grid 66 x 256.
__global__ __launch_bounds__(256) void ctxred(
    const float* __restrict__ ctxp, const float* __restrict__ skp,
    float* __restrict__ ctx, float* __restrict__ Sk)
{
    const int o = blockIdx.x * 256 + threadIdx.x;   // 0..16895
    if (o < 16384) {
        float a = 0.0f;
        for (int s = 0; s < NSPLIT; ++s) a += ctxp[(size_t)s * 16384 + o];
        ctx[o] = a;
    } else {
        const int c = o - 16384;
        float a = 0.0f;
        for (int s = 0; s < NSPLIT; ++s) a += skp[(size_t)s * 512 + c];
        Sk[c] = a;
    }
}

// ---------------------------------------------------------------------------
// W'[b][n][h*32+d] = (1/sqrt(dk)) * (1/Sk[d]) * sum_e ctx[b][h][d][e] * Wo[h*32+e][n]
// ---------------------------------------------------------------------------
__global__ __launch_bounds__(256) void ctxwo_kernel(
    const float* __restrict__ ctx, const float* __restrict__ Sk,
    const unsigned short* __restrict__ wo_t, unsigned short* __restrict__ wp)
{
    const int h = blockIdx.x, b = blockIdx.y;
    const int n = threadIdx.x;
    __shared__ float cl[1024];
    __shared__ float sdk[32];
    {
        const float* cp = ctx + (size_t)(b * 8 + h) * 1024;
        *(float4*)&cl[n * 4] = *(const float4*)&cp[n * 4];
    }
    if (n < 32) sdk[n] = 0.17677669529663687f / Sk[b * 256 + h * 32 + n];
    __syncthreads();
    float w[32];
    const unsigned short* wop = wo_t + (size_t)n * 256 + h * 32;
    #pragma unroll
    for (int e = 0; e < 32; ++e) w[e] = bf2f(wop[e]);
    unsigned short outv[32];
    #pragma unroll
    for (int d = 0; d < 32; ++d) {
        float acc = 0.0f;
        #pragma unroll
        for (int e = 0; e < 32; ++e) acc += cl[d * 32 + e] * w[e];
        outv[d] = f2bf(acc * sdk[d]);
    }
    unsigned short* op = wp + (size_t)b * 65536 + (size_t)n * 256 + h * 32;
    #pragma unroll
    for (int d = 0; d < 32; d += 8)
        *(uint4*)(op + d) = *(uint4*)(outv + d);
}

// ---------------------------------------------------------------------------
// t = LayerNorm(t + add(bf16)); writes t f32 in place (+ optional bf16 copy)
// ---------------------------------------------------------------------------
template<int WB>
__global__ __launch_bounds__(256) void ln_kernel(
    float* __restrict__ t, const unsigned short* __restrict__ add,
    const float* __restrict__ g, const float* __restrict__ bta,
    unsigned short* __restrict__ tbf)
{
    const int row = blockIdx.x;
    const int c = threadIdx.x;
    const int lane = c & 63, wave = c >> 6;
    const size_t off = (size_t)row * 256 + c;
    const float v = t[off] + bf2f(add[off]);
    __shared__ float red[8];
    float s = v;
    #pragma unroll
    for (int o = 32; o; o >>= 1) s += __shfl_xor(s, o, 64);
    if (lane == 0) red[wave] = s;
    __syncthreads();
    const float mu = (red[0] + red[1] + red[2] + red[3]) * (1.0f / 256.0f);
    const float dv = v - mu;
    float s2 = dv * dv;
    #pragma unroll
    for (int o = 32; o; o >>= 1) s2 += __shfl_xor(s2, o, 64);
    if (lane == 0) red[wave + 4] = s2;
    __syncthreads();
    const float var = (red[4] + red[5] + red[6] + red[7]) * (1.0f / 256.0f);
    const float o = dv * rsqrtf(var + 1e-6f) * g[c] + bta[c];
    t[off] = o;
    if (WB) tbf[off] = f2bf(o);
}

// ---------------------------------------------------------------------------
// depthwise 3x3x3 conv + residual, register-resident weights + sliding window.
// ---------------------------------------------------------------------------
template<int WB>
__global__ __launch_bounds__(256) void posconv_kernel(
    const float* __restrict__ tin, const float* __restrict__ pw,
    const float* __restrict__ pb, float* __restrict__ outp,
    unsigned short* __restrict__ tbfp)
{
    const int hw = blockIdx.x;            // 0..575
    const int b  = blockIdx.y;
    const int hh = hw / 24, ww = hw % 24;
    const int c  = threadIdx.x;

    float w[27];
    #pragma unroll
    for (int k = 0; k < 27; ++k) w[k] = pw[c * 27 + k];
    const float bias = pb[c];

    const float* base = tin + (size_t)b * NTOK * 256 + c;

    const float* colp[9];
    bool colok[9];
    #pragma unroll
    for (int dh = -1; dh <= 1; ++dh)
        #pragma unroll
        for (int dw = -1; dw <= 1; ++dw) {
            const int j = (dh + 1) * 3 + (dw + 1);
            const int h2 = hh + dh, w2 = ww + dw;
            colok[j] = ((unsigned)h2 < 24u) & ((unsigned)w2 < 24u);
            colp[j] = base + (size_t)((h2 * 24 + w2) * 24) * 256;
        }

    float win[9][3];
    #pragma unroll
    for (int j = 0; j < 9; ++j) {
        win[j][0] = 0.0f;
        win[j][1] = colok[j] ? colp[j][0] : 0.0f;
    }

    float* ob = outp + ((size_t)b * NTOK + (size_t)hw * 24) * 256 + c;
    unsigned short* tb = WB ? (tbfp + ((size_t)b * NTOK + (size_t)hw * 24) * 256 + c)
                            : (unsigned short*)nullptr;

    for (int d = 0; d < 24; ++d) {
        #pragma unroll
        for (int j = 0; j < 9; ++j)
            win[j][2] = (colok[j] && d < 23) ? colp[j][(d + 1) * 256] : 0.0f;

        float acc = bias + win[4][1];
        #pragma unroll
        for (int j = 0; j < 9; ++j) {
            acc += w[j * 3 + 0] * win[j][0];
            acc += w[j * 3 + 1] * win[j][1];
            acc += w[j * 3 + 2] * win[j][2];
        }
        ob[d * 256] = acc;
        if (WB) tb[d * 256] = f2bf(acc);

        #pragma unroll
        for (int j = 0; j < 9; ++j) { win[j][0] = win[j][1]; win[j][1] = win[j][2]; }
    }
}

// ---------------------------------------------------------------------------
// final transpose: t [MTOT][256] f32 -> out [B][256][NTOK] (LDS tiled)
// ---------------------------------------------------------------------------
__global__ __launch_bounds__(256) void tr_out(
    const float* __restrict__ tin, float* __restrict__ outp)
{
    __shared__ float tile[32][33];
    const int m0 = blockIdx.x * 32;
    const int c0 = blockIdx.y * 32;
    const int t = threadIdx.x;
    const int tc = t & 31, tr = t >> 5;
    #pragma unroll
    for (int r = 0; r < 4; ++r)
        tile[tr + r * 8][tc] = tin[(size_t)(m0 + tr + r * 8) * 256 + c0 + tc];
    __syncthreads();
    const int b = (m0 >= NTOK) ? 1 : 0;
    const int n0 = m0 - b * NTOK;
    #pragma unroll
    for (int r = 0; r < 4; ++r)
        outp[((size_t)b * 256 + c0 + tr + r * 8) * NTOK + n0 + tc] = tile[tc][tr + r * 8];
}

// ---------------------------------------------------------------------------
// launch
// ---------------------------------------------------------------------------
extern "C" void kernel_launch(void* const* d_in, const int* in_sizes, int n_in,
                              void* d_out, int out_size, void* d_ws, size_t ws_size,
                              hipStream_t stream)
{
    (void)in_sizes; (void)n_in; (void)out_size; (void)ws_size;
    const float* x     = (const float*)d_in[0];
    const float* Wx_w  = (const float*)d_in[1];
    const float* Wx_b  = (const float*)d_in[2];
    const float* Wq    = (const float*)d_in[3];
    const float* bq    = (const float*)d_in[4];
    const float* Wk    = (const float*)d_in[5];
    const float* bk    = (const float*)d_in[6];
    const float* Wv    = (const float*)d_in[7];
    const float* bv    = (const float*)d_in[8];
    const float* Wo    = (const float*)d_in[9];
    const float* bo    = (const float*)d_in[10];
    const float* ln1_g = (const float*)d_in[11];
    const float* ln1_b = (const float*)d_in[12];
    const float* ln2_g = (const float*)d_in[13];
    const float* ln2_b = (const float*)d_in[14];
    const float* fw1   = (const float*)d_in[15];
    const float* fb1   = (const float*)d_in[16];
    const float* fw2   = (const float*)d_in[17];
    const float* fb2   = (const float*)d_in[18];
    const float* pw    = (const float*)d_in[19];
    const float* pb    = (const float*)d_in[20];
    float* out = (float*)d_out;

    char* p = (char*)d_ws;
    float* tA            = (float*)p;          p += (size_t)MTOT * 256 * 4;
    float* tB            = (float*)p;          p += (size_t)MTOT * 256 * 4;
    unsigned short* tbf  = (unsigned short*)p; p += (size_t)MTOT * 256 * 2;
    unsigned short* qkv  = (unsigned short*)p; p += (size_t)MTOT * 768 * 2;
    unsigned short* hbf  = (unsigned short*)p; p += (size_t)MTOT * 512 * 2;   // also kvT
    unsigned short* ob   = (unsigned short*)p; p += (size_t)MTOT * 256 * 2;
    unsigned short* xbf  = (unsigned short*)p; p += (size_t)MTOT * 128 * 2;
    unsigned short* wqkv_t = (unsigned short*)p; p += (size_t)786432 * 2;
    unsigned short* wo_t   = (unsigned short*)p; p += (size_t)262144 * 2;
    unsigned short* w1_t   = (unsigned short*)p; p += (size_t)524288 * 2;
    unsigned short* w2_t   = (unsigned short*)p; p += (size_t)524288 * 2;
    unsigned short* wx_bf  = (unsigned short*)p; p += (size_t)32768 * 2;
    unsigned short* wp     = (unsigned short*)p; p += (size_t)BATCH * 65536 * 2;
    float* bqkv = (float*)p; p += 3072 * 4;
    float* ctx  = (float*)p; p += 16384 * 4;
    float* Sk   = (float*)p; p += 512 * 4;
    float* ctxp = (float*)p; p += (size_t)NSPLIT * 16384 * 4;
    float* skp  = (float*)p; p += (size_t)NSPLIT * 512 * 4;
    unsigned short* kvT = hbf;   // overlays FFN hidden (disjoint lifetime)

    hipLaunchKernelGGL(conv_weights, dim3(8333), dim3(256), 0, stream,
                       Wq, Wk, Wv, Wo, fw1, fw2, Wx_w, bq, bk, bv,
                       wqkv_t, wo_t, w1_t, w2_t, wx_bf, bqkv);
    hipLaunchKernelGGL(conv_x, dim3(NTOK / 32, CIN / 32, BATCH), dim3(256), 0, stream,
                       x, xbf);

    // input 1x1x1 conv + relu -> tA f32 + tbf bf16
    hipLaunchKernelGGL((gemm_bf16<1, 2>), dim3(216, 2, 1), dim3(256), 0, stream,
                       xbf, CIN, wx_bf, CIN, Wx_b, tA, tbf, 256, CIN,
                       (long)0, (long)0, (long)0);

    for (int i = 0; i < NLAYERS; ++i) {
        float* tin  = (i & 1) ? tB : tA;
        float* tout = (i & 1) ? tA : tB;

        // fused QKV: [M,256] x [256,768]
        hipLaunchKernelGGL((gemm_bf16<0, 1>), dim3(216, 6, 1), dim3(256), 0, stream,
                           tbf, 256, wqkv_t + (size_t)i * 196608, 256,
                           bqkv + i * 768, nullptr, qkv, 768, 256,
                           (long)0, (long)0, (long)0);

        // ctx path: transpose -> MFMA split-K -> reduce (no atomics, no memset)
        hipLaunchKernelGGL(kvt_kernel, dim3(NTOK / 64, NHEAD, BATCH), dim3(256), 0, stream,
                           qkv, kvT);
        hipLaunchKernelGGL(ctx_mfma, dim3(NSPLIT, NHEAD, BATCH), dim3(256), 0, stream,
                           kvT, ctxp, skp);
        hipLaunchKernelGGL(ctxred, dim3(66), dim3(256), 0, stream, ctxp, skp, ctx, Sk);

        // q softmax in place + W' = (ctx/Sk) @ Wo (per batch)
        hipLaunchKernelGGL(qsm_kernel, dim3(3456), dim3(256), 0, stream, qkv);
        hipLaunchKernelGGL(ctxwo_kernel, dim3(NHEAD, BATCH), dim3(256), 0, stream,
                           ctx, Sk, wo_t + (size_t)i * 65536, wp);

        // o_proj = qs @ W' + bo  (batched over z)
        hipLaunchKernelGGL((gemm_bf16<0, 1>), dim3(108, 2, BATCH), dim3(256), 0, stream,
                           qkv, 768, wp, 256, bo + i * 256, nullptr, ob, 256, 256,
                           (long)NTOK * 768, (long)65536, (long)NTOK * 256);

        hipLaunchKernelGGL((ln_kernel<1>), dim3(MTOT), dim3(256), 0, stream,
                           tin, ob, ln1_g + i * 256, ln1_b + i * 256, tbf);

        // FFN (hbf free again: kvT consumed)
        hipLaunchKernelGGL((gemm_bf16<2, 1>), dim3(216, 4, 1), dim3(256), 0, stream,
                           tbf, 256, w1_t + (size_t)i * 131072, 256,
                           fb1 + i * 512, nullptr, hbf, 512, 256,
                           (long)0, (long)0, (long)0);
        hipLaunchKernelGGL((gemm_bf16<0, 1>), dim3(216, 2, 1), dim3(256), 0, stream,
                           hbf, 512, w2_t + (size_t)i * 131072, 512,
                           fb2 + i * 256, nullptr, ob, 256, 512,
                           (long)0, (long)0, (long)0);
        hipLaunchKernelGGL((ln_kernel<0>), dim3(MTOT), dim3(256), 0, stream,
                           tin, ob, ln2_g + i * 256, ln2_b + i * 256, nullptr);

        // depthwise conv + residual -> tout f32 (+ tbf bf16 except last layer)
        if (i < NLAYERS - 1)
            hipLaunchKernelGGL((posconv_kernel<1>), dim3(576, BATCH), dim3(256), 0, stream,
                               tin, pw + (size_t)i * 6912, pb + i * 256, tout, tbf);
        else
            hipLaunchKernelGGL((posconv_kernel<0>), dim3(576, BATCH), dim3(256), 0, stream,
                               tin, pw + (size_t)i * 6912, pb + i * 256, tout, nullptr);
    }

    // layer 3 wrote tA
    hipLaunchKernelGGL(tr_out, dim3(MTOT / 32, 8), dim3(256), 0, stream, tA, out);
}